// Round 4
// baseline (177.176 us; speedup 1.0000x reference)
//
#include <hip/hip_runtime.h>
#include <math.h>

#define N_Q 4096
#define L_K 64
#define M_D 256

typedef float f32x16 __attribute__((ext_vector_type(16)));
typedef __bf16 b16x8 __attribute__((ext_vector_type(8)));
union F8 { uint4 u; unsigned short s[8]; b16x8 v; };

__device__ __forceinline__ unsigned short f2bf(float x) {
  unsigned u = __float_as_uint(x);
  return (unsigned short)((u + 0x7fffu + ((u >> 16) & 1u)) >> 16);  // RNE
}

__global__ void k_zero(int* __restrict__ c) { if (threadIdx.x == 0) c[0] = 0; }

// ---- prep: spec canonicalize + out2 echo, Wv^T, Wk B-frag image, row compaction ----
__global__ __launch_bounds__(256) void k_prep(const unsigned char* __restrict__ raw,
                                              unsigned char* __restrict__ spec,
                                              float* __restrict__ out2,
                                              const float* __restrict__ wv,
                                              float* __restrict__ wvt,
                                              const float* __restrict__ wk,
                                              unsigned short* __restrict__ wkf,
                                              const int* __restrict__ lin,
                                              int* __restrict__ cnt,
                                              int* __restrict__ rowinfo,
                                              int* __restrict__ rowlin) {
  int v = 0;
  for (int i = threadIdx.x; i < 4096; i += 256)
    if (i & 3) v |= raw[i];
  int f = __syncthreads_or(v);            // 1 = byte layout, 0 = int32 layout
  const int gi = blockIdx.x * 256 + threadIdx.x;   // covers N*L = 262144
  const int lane = threadIdx.x & 63;               // == gi&63 == l (wave = one n)
  bool b = f ? (raw[gi] != 0) : (((const int*)raw)[gi] != 0);
  spec[gi] = b ? 1 : 0;
  out2[gi] = b ? 1.0f : 0.0f;

  // compaction: one wave == one n (64 consecutive gi)
  int li = lin[gi];
  unsigned long long mask = __ballot(b);
  int b0 = 0;
  if (lane == 0) b0 = atomicAdd(cnt, __popcll(mask));
  b0 = __shfl(b0, 0);
  if (b) {
    int rank = __popcll(mask & ((1ull << lane) - 1));
    rowinfo[b0 + rank] = gi;              // n*64 + l
    rowlin[b0 + rank] = li;
  }

  if (gi < 65536) {
    wvt[(gi & 255) * 256 + (gi >> 8)] = wv[gi];    // wvt[j][m] = wv[m][j]
    // B-fragment image for mfma_32x32x16_bf16: slot ((tt*16+ks)*64+lane)*8+j
    int row = gi >> 8, k = gi & 255;               // wk row (out col), k
    int tt = row >> 5, c32 = row & 31;
    int ks = k >> 4, kg = (k >> 3) & 1, j = k & 7;
    wkf[(((tt * 16 + ks) * 64) + kg * 32 + c32) * 8 + j] = f2bf(wk[gi]);
  }
}

// ---- k_scores: compacted K-proj GEMM + RoPE + raw scores (no barriers, no block LDS) ----
// 4096 blocks x 256 thr (4 waves). Wave: rg=w>>1 rows (32), ch=w&1 col-half (4 heads).
__global__ __launch_bounds__(256, 4) void k_scores(
    const float* __restrict__ sv, const float* __restrict__ q,
    const unsigned short* __restrict__ wkf, const float* __restrict__ pos,
    const float* __restrict__ freqs, const int* __restrict__ cnt,
    const int* __restrict__ rowinfo, const int* __restrict__ rowlin,
    float* __restrict__ scores) {
  const int total = cnt[0];
  const int base = blockIdx.x * 64;
  if (base >= total) return;

  __shared__ float kep[4][1056];          // 32 rows x stride 33, per wave (16.9KB)
  const int tid = threadIdx.x, lane = tid & 63, w = tid >> 6;
  const int c32 = lane & 31, kg = lane >> 5;
  const int rg = w >> 1, ch = w & 1;

  const int idx = base + rg * 32 + c32;
  const bool valid = idx < total;
  const int info = valid ? rowinfo[idx] : 0;
  const float* arow = sv + (size_t)(valid ? rowlin[idx] : 0) * 256;
  const char* fb = (const char*)wkf + ch * 65536 + lane * 16;

  f32x16 acc[4];
  #pragma unroll
  for (int t = 0; t < 4; ++t)
    #pragma unroll
    for (int r = 0; r < 16; ++r) acc[t][r] = 0.0f;

  #pragma unroll
  for (int ks = 0; ks < 16; ++ks) {
    const float* ap = arow + ks * 16 + kg * 8;
    float4 a0 = *(const float4*)(ap);
    float4 a1 = *(const float4*)(ap + 4);
    F8 af;
    af.s[0] = f2bf(a0.x); af.s[1] = f2bf(a0.y); af.s[2] = f2bf(a0.z); af.s[3] = f2bf(a0.w);
    af.s[4] = f2bf(a1.x); af.s[5] = f2bf(a1.y); af.s[6] = f2bf(a1.z); af.s[7] = f2bf(a1.w);
    #pragma unroll
    for (int t = 0; t < 4; ++t) {
      F8 bf;
      bf.u = *(const uint4*)(fb + (t * 16 + ks) * 1024);
      acc[t] = __builtin_amdgcn_mfma_f32_32x32x16_bf16(af.v, bf.v, acc[t], 0, 0, 0);
    }
  }

  // ---- wave-private transpose + RoPE + q-dot + scattered score write ----
  const int riw = lane >> 1, dh = lane & 1;
  const int rinfo = __shfl(info, riw);               // (n*64+l) of row riw
  const bool rvalid = (base + rg * 32 + riw) < total;
  const int nn_ = rinfo >> 6, ll = rinfo & 63;
  const float pp0 = pos[rinfo * 3], pp1 = pos[rinfo * 3 + 1], pp2 = pos[rinfo * 3 + 2];
  float* myk = kep[w];

  #pragma unroll
  for (int hl = 0; hl < 4; ++hl) {
    const int h = ch * 4 + hl;
    #pragma unroll
    for (int r = 0; r < 16; ++r) {
      int rw = ((lane >> 5) << 2) + (r & 3) + ((r >> 2) << 3);   // m74/m101 D-layout
      myk[rw * 33 + c32] = acc[hl][r];
    }
    asm volatile("s_waitcnt lgkmcnt(0)" ::: "memory");
    const float* kr = myk + riw * 33 + (dh << 4);
    const float* qb = q + nn_ * 256 + h * 32 + (dh << 4);
    const float* F0 = freqs + h * 16 + (dh << 3);
    const float* F1 = F0 + 128;
    const float* F2 = F0 + 256;
    float s = 0.f;
    #pragma unroll
    for (int j = 0; j < 8; ++j) {
      float ang = pp0 * F0[j] + pp1 * F1[j] + pp2 * F2[j];
      float sn, cs;
      __sincosf(ang, &sn, &cs);
      float ke = kr[2 * j], ko = kr[2 * j + 1];
      float2 qq = *(const float2*)(qb + 2 * j);
      s += ke * (cs * qq.x + sn * qq.y) + ko * (cs * qq.y - sn * qq.x);
    }
    s += __shfl_xor(s, 1);
    if (dh == 0 && rvalid)
      scores[(nn_ * 8 + h) * 64 + ll] = s * 0.0625f;    // 1/sqrt(256)
    asm volatile("s_waitcnt lgkmcnt(0)" ::: "memory");
  }
}

// ---- k_vout: masked softmax + compacted attn-weighted gather + Wv projection ----
__global__ __launch_bounds__(256, 6) void k_vout(
    const float* __restrict__ sv, const int* __restrict__ lin,
    const unsigned char* __restrict__ spec, const float* __restrict__ scores,
    const float* __restrict__ wvt, float* __restrict__ out) {
  __shared__ float attn_s[2][64][8];       // [nn][l][h]
  __shared__ float agg_s[2][8][256];
  __shared__ int list_s[2][64];
  __shared__ int cnt_s[2];
  __shared__ int lin_l[128];
  __shared__ unsigned char spec_l[128];
  const int tid = threadIdx.x, lane = tid & 63, w = tid >> 6;
  const int n0 = blockIdx.x * 2;

  if (tid < 128) {
    lin_l[tid] = lin[n0 * 64 + tid];
    spec_l[tid] = spec[n0 * 64 + tid];
  }
  __syncthreads();

  // softmax: 16 (n,h) units, 4 per wave
  #pragma unroll
  for (int uu = 0; uu < 4; ++uu) {
    int unit = w * 4 + uu;                 // nl*8 + h
    int nl = unit >> 3, h = unit & 7;
    bool sp = spec_l[nl * 64 + lane] != 0;
    float v = sp ? scores[((n0 + nl) * 8 + h) * 64 + lane] : -__builtin_inff();
    float mx = v;
    #pragma unroll
    for (int o = 32; o; o >>= 1) mx = fmaxf(mx, __shfl_xor(mx, o));
    float e = sp ? __expf(v - mx) : 0.f;
    float sm = e;
    #pragma unroll
    for (int o = 32; o; o >>= 1) sm += __shfl_xor(sm, o);
    attn_s[nl][lane][h] = (sm > 0.f) ? e / sm : 0.f;
  }
  if (w == 0) {                            // packed gather lists
    #pragma unroll
    for (int nn = 0; nn < 2; ++nn) {
      bool p = spec_l[nn * 64 + lane] != 0;
      unsigned long long mask = __ballot(p);
      if (p) {
        int rank = __popcll(mask & ((1ull << lane) - 1));
        list_s[nn][rank] = (lin_l[nn * 64 + lane] << 6) | lane;
      }
      if (lane == 0) cnt_s[nn] = __popcll(mask);
    }
  }
  __syncthreads();

  const int m = tid;
  float ga[2][8];
  #pragma unroll
  for (int a = 0; a < 2; ++a)
    #pragma unroll
    for (int h = 0; h < 8; ++h) ga[a][h] = 0.f;

  #pragma unroll
  for (int nn = 0; nn < 2; ++nn) {
    const int cntn = cnt_s[nn];
    #pragma unroll 4
    for (int i = 0; i < cntn; ++i) {
      int pk = list_s[nn][i];
      float gv = sv[(size_t)(pk >> 6) * 256 + m];
      const float4* ap = (const float4*)&attn_s[nn][pk & 63][0];
      float4 aA = ap[0], aB = ap[1];
      ga[nn][0] += aA.x * gv; ga[nn][1] += aA.y * gv;
      ga[nn][2] += aA.z * gv; ga[nn][3] += aA.w * gv;
      ga[nn][4] += aB.x * gv; ga[nn][5] += aB.y * gv;
      ga[nn][6] += aB.z * gv; ga[nn][7] += aB.w * gv;
    }
  }
  #pragma unroll
  for (int nn = 0; nn < 2; ++nn)
    #pragma unroll
    for (int h = 0; h < 8; ++h) agg_s[nn][h][m] = ga[nn][h];
  __syncthreads();

  const int h = m >> 5;
  const float* a0p = &agg_s[0][h][0];
  const float* a1p = &agg_s[1][h][0];
  float o0 = 0.f, o1 = 0.f;
  #pragma unroll 8
  for (int mm = 0; mm < 256; ++mm) {
    float wvv = wvt[mm * 256 + m];
    o0 += a0p[mm] * wvv;
    o1 += a1p[mm] * wvv;
  }
  out[n0 * 256 + m] = o0;
  out[(n0 + 1) * 256 + m] = o1;
}

extern "C" void kernel_launch(void* const* d_in, const int* in_sizes, int n_in,
                              void* d_out, int out_size, void* d_ws, size_t ws_size,
                              hipStream_t stream) {
  const float* sv  = (const float*)d_in[0];
  const int* lin   = (const int*)d_in[1];
  const unsigned char* raw = (const unsigned char*)d_in[2];
  const float* q   = (const float*)d_in[3];
  const float* wk  = (const float*)d_in[4];
  const float* wv  = (const float*)d_in[5];
  const float* pos = (const float*)d_in[6];
  const float* fq  = (const float*)d_in[7];
  float* out = (float*)d_out;
  char* ws = (char*)d_ws;

  int* cnt            = (int*)ws;                          // @0
  unsigned char* spec = (unsigned char*)(ws + 1024);       // 262144
  float* wvt          = (float*)(ws + 263168);             // 262144
  unsigned short* wkf = (unsigned short*)(ws + 525312);    // 131072
  float* scores       = (float*)(ws + 656384);             // 8388608
  int* rowinfo        = (int*)(ws + 9044992);              // 1048576
  int* rowlin         = (int*)(ws + 10093568);             // 1048576 -> ~11.1MB

  k_zero<<<1, 64, 0, stream>>>(cnt);
  k_prep<<<1024, 256, 0, stream>>>(raw, spec, out + N_Q * M_D, wv, wvt, wk, wkf,
                                   lin, cnt, rowinfo, rowlin);
  k_scores<<<4096, 256, 0, stream>>>(sv, q, wkf, pos, fq, cnt, rowinfo, rowlin, scores);
  k_vout<<<2048, 256, 0, stream>>>(sv, lin, spec, scores, wvt, out);
}

// Round 5
// 151.524 us; speedup vs baseline: 1.1693x; 1.1693x over previous
//
#include <hip/hip_runtime.h>
#include <math.h>

#define N_Q 4096
#define L_K 64
#define M_D 256

typedef float f32x16 __attribute__((ext_vector_type(16)));
typedef __bf16 b16x8 __attribute__((ext_vector_type(8)));
union F8 { uint4 u; unsigned short s[8]; b16x8 v; };

__device__ __forceinline__ unsigned short f2bf(float x) {
  unsigned u = __float_as_uint(x);
  return (unsigned short)((u + 0x7fffu + ((u >> 16) & 1u)) >> 16);  // RNE
}

__global__ void k_zero(int* __restrict__ c) { if (threadIdx.x == 0) c[0] = 0; }

// ---- prep: spec canonicalize + out2, Wv^T, Wk frag image, row compaction ----
__global__ __launch_bounds__(256) void k_prep(const unsigned char* __restrict__ raw,
                                              unsigned char* __restrict__ spec,
                                              float* __restrict__ out2,
                                              const float* __restrict__ wv,
                                              float* __restrict__ wvt,
                                              const float* __restrict__ wk,
                                              unsigned short* __restrict__ wkf,
                                              const int* __restrict__ lin,
                                              int* __restrict__ cnt,
                                              int* __restrict__ rowinfo,
                                              int* __restrict__ rowlin) {
  __shared__ int wbase[4];
  int v = 0;
  for (int i = threadIdx.x; i < 4096; i += 256)
    if (i & 3) v |= raw[i];
  int f = __syncthreads_or(v);            // 1 = byte layout, 0 = int32 layout
  const int gi = blockIdx.x * 256 + threadIdx.x;   // covers N*L = 262144
  const int lane = threadIdx.x & 63, w = threadIdx.x >> 6;
  bool b = f ? (raw[gi] != 0) : (((const int*)raw)[gi] != 0);
  spec[gi] = b ? 1 : 0;
  out2[gi] = b ? 1.0f : 0.0f;

  int li = lin[gi];
  unsigned long long mask = __ballot(b);
  if (lane == 0) wbase[w] = __popcll(mask);
  __syncthreads();
  if (threadIdx.x == 0) {                 // one atomic per block
    int t0 = wbase[0], t1 = wbase[1], t2 = wbase[2], t3 = wbase[3];
    int bs = atomicAdd(cnt, t0 + t1 + t2 + t3);
    wbase[0] = bs; wbase[1] = bs + t0; wbase[2] = bs + t0 + t1; wbase[3] = bs + t0 + t1 + t2;
  }
  __syncthreads();
  if (b) {
    int rank = __popcll(mask & ((1ull << lane) - 1));
    int p = wbase[w] + rank;
    rowinfo[p] = gi;                      // n*64 + l
    rowlin[p] = li;
  }

  if (gi < 65536) {
    wvt[(gi & 255) * 256 + (gi >> 8)] = wv[gi];    // wvt[j][m] = wv[m][j]
    // Wk fragment image (lane-ordered for mfma_32x32x16_bf16)
    int row = gi >> 8, k = gi & 255;               // wk row (out col), k
    int tt = row >> 5, c32 = row & 31;
    int ks = k >> 4, kg = (k >> 3) & 1, j = k & 7;
    wkf[(((tt * 16 + ks) * 64) + kg * 32 + c32) * 8 + j] = f2bf(wk[gi]);
  }
}

// ---- k_scores: swapped-operand K-proj GEMM + in-register RoPE + scores ----
// A = Wk frags (L2-streamed), B = gathered rows -> C cols (lane&31) = data rows.
// 4096 blocks x 256 thr (4 waves); wave (rg,ch): 32 packed rows, heads ch*4..+3.
// No LDS, no barriers. acc = 4 x f32x16 = 64 AGPR.
__global__ __launch_bounds__(256, 4) void k_scores(
    const float* __restrict__ sv, const float* __restrict__ q,
    const unsigned short* __restrict__ wkf, const float* __restrict__ pos,
    const float* __restrict__ freqs, const int* __restrict__ cnt,
    const int* __restrict__ rowinfo, const int* __restrict__ rowlin,
    float* __restrict__ scores) {
  const int total = cnt[0];
  const int base = blockIdx.x * 64;
  if (base >= total) return;

  const int tid = threadIdx.x, lane = tid & 63, w = tid >> 6;
  const int c32 = lane & 31, kg = lane >> 5, hi = kg;
  const int rg = w >> 1, ch = w & 1;

  const int idx = base + rg * 32 + c32;
  const bool valid = idx < total;
  const int info = valid ? rowinfo[idx] : 0;                 // n*64+l (lane-local row)
  const float* brow = sv + (size_t)(valid ? rowlin[idx] : 0) * 256;
  const char* fb = (const char*)wkf + ch * 65536 + lane * 16;

  f32x16 acc[4];
  #pragma unroll
  for (int t = 0; t < 4; ++t)
    #pragma unroll
    for (int r = 0; r < 16; ++r) acc[t][r] = 0.0f;

  float4 b0 = *(const float4*)(brow + kg * 8);
  float4 b1 = *(const float4*)(brow + kg * 8 + 4);
  #pragma unroll
  for (int ks = 0; ks < 16; ++ks) {
    int nk = (ks < 15) ? ks + 1 : 15;                        // 1-deep prefetch
    float4 n0 = *(const float4*)(brow + nk * 16 + kg * 8);
    float4 n1 = *(const float4*)(brow + nk * 16 + kg * 8 + 4);
    F8 bf;
    bf.s[0] = f2bf(b0.x); bf.s[1] = f2bf(b0.y); bf.s[2] = f2bf(b0.z); bf.s[3] = f2bf(b0.w);
    bf.s[4] = f2bf(b1.x); bf.s[5] = f2bf(b1.y); bf.s[6] = f2bf(b1.z); bf.s[7] = f2bf(b1.w);
    #pragma unroll
    for (int t = 0; t < 4; ++t) {
      F8 af;
      af.u = *(const uint4*)(fb + (t * 16 + ks) * 1024);     // A = Wk (coalesced, L2)
      acc[t] = __builtin_amdgcn_mfma_f32_32x32x16_bf16(af.v, bf.v, acc[t], 0, 0, 0);
    }
    b0 = n0; b1 = n1;
  }

  // ---- in-register RoPE + q-dot; lane owns row `info`, d-set: {g*8+hi*4 .. +3} ----
  const int nn_ = info >> 6, ll = info & 63;
  const float pp0 = pos[info * 3], pp1 = pos[info * 3 + 1], pp2 = pos[info * 3 + 2];
  #pragma unroll
  for (int t = 0; t < 4; ++t) {
    const int h = ch * 4 + t;
    const float* qh = q + nn_ * 256 + h * 32;
    const float* F = freqs + h * 16;          // F[p*128 + jj], jj = d/2
    float s = 0.f;
    #pragma unroll
    for (int g = 0; g < 4; ++g) {
      #pragma unroll
      for (int pr = 0; pr < 2; ++pr) {
        const int d0 = g * 8 + hi * 4 + pr * 2;              // even d of the pair
        const int jj = d0 >> 1;
        const int r = g * 4 + pr * 2;                        // rw(r)= pr*2+8g+4hi = d0
        float ke = acc[t][r], ko = acc[t][r + 1];
        float ang = pp0 * F[jj] + pp1 * F[128 + jj] + pp2 * F[256 + jj];
        float sn, cs;
        __sincosf(ang, &sn, &cs);
        float2 qq = *(const float2*)(qh + d0);
        s += ke * (cs * qq.x + sn * qq.y) + ko * (cs * qq.y - sn * qq.x);
      }
    }
    s += __shfl_xor(s, 32);                  // combine hi halves
    if (hi == 0 && valid)
      scores[(nn_ * 8 + h) * 64 + ll] = s * 0.0625f;         // 1/sqrt(256)
  }
}

// ---- k_vout: softmax + compacted attn-weighted gather + Wv projection (1 n/block) ----
__global__ __launch_bounds__(256, 8) void k_vout(
    const float* __restrict__ sv, const int* __restrict__ lin,
    const unsigned char* __restrict__ spec, const float* __restrict__ scores,
    const float* __restrict__ wvt, float* __restrict__ out) {
  __shared__ float attn_s[64][8];
  __shared__ float agg_s[8][256];
  __shared__ int list_s[64];
  __shared__ int cnt_s;
  __shared__ int lin_l[64];
  __shared__ unsigned char spec_l[64];
  const int tid = threadIdx.x, lane = tid & 63, w = tid >> 6;
  const int n = blockIdx.x;

  if (tid < 64) {
    lin_l[tid] = lin[n * 64 + tid];
    spec_l[tid] = spec[n * 64 + tid];
  }
  __syncthreads();

  const bool sp = spec_l[lane] != 0;
  #pragma unroll
  for (int uu = 0; uu < 2; ++uu) {          // softmax: 8 heads, 2 per wave
    int h = w * 2 + uu;
    float v = sp ? scores[(n * 8 + h) * 64 + lane] : -__builtin_inff();
    float mx = v;
    #pragma unroll
    for (int o = 32; o; o >>= 1) mx = fmaxf(mx, __shfl_xor(mx, o));
    float e = sp ? __expf(v - mx) : 0.f;
    float sm = e;
    #pragma unroll
    for (int o = 32; o; o >>= 1) sm += __shfl_xor(sm, o);
    attn_s[lane][h] = (sm > 0.f) ? e / sm : 0.f;
  }
  if (w == 0) {                             // packed gather list
    unsigned long long mask = __ballot(sp);
    if (sp) {
      int rank = __popcll(mask & ((1ull << lane) - 1));
      list_s[rank] = (lin_l[lane] << 6) | lane;
    }
    if (lane == 0) cnt_s = __popcll(mask);
  }
  __syncthreads();

  const int m = tid;
  float ga[8];
  #pragma unroll
  for (int h = 0; h < 8; ++h) ga[h] = 0.f;
  const int cn = cnt_s;
  #pragma unroll 4
  for (int i = 0; i < cn; ++i) {
    int pk = list_s[i];
    float gv = sv[(size_t)(pk >> 6) * 256 + m];     // coalesced 1KB row
    const float4* ap = (const float4*)&attn_s[pk & 63][0];
    float4 aA = ap[0], aB = ap[1];                  // LDS broadcast
    ga[0] += aA.x * gv; ga[1] += aA.y * gv; ga[2] += aA.z * gv; ga[3] += aA.w * gv;
    ga[4] += aB.x * gv; ga[5] += aB.y * gv; ga[6] += aB.z * gv; ga[7] += aB.w * gv;
  }
  #pragma unroll
  for (int h = 0; h < 8; ++h) agg_s[h][m] = ga[h];
  __syncthreads();

  const int h = m >> 5;
  const float* ap = &agg_s[h][0];
  float o = 0.f;
  #pragma unroll 8
  for (int mm = 0; mm < 256; ++mm)
    o += ap[mm] * wvt[mm * 256 + m];        // broadcast LDS x coalesced L2
  out[n * 256 + m] = o;
}

extern "C" void kernel_launch(void* const* d_in, const int* in_sizes, int n_in,
                              void* d_out, int out_size, void* d_ws, size_t ws_size,
                              hipStream_t stream) {
  const float* sv  = (const float*)d_in[0];
  const int* lin   = (const int*)d_in[1];
  const unsigned char* raw = (const unsigned char*)d_in[2];
  const float* q   = (const float*)d_in[3];
  const float* wk  = (const float*)d_in[4];
  const float* wv  = (const float*)d_in[5];
  const float* pos = (const float*)d_in[6];
  const float* fq  = (const float*)d_in[7];
  float* out = (float*)d_out;
  char* ws = (char*)d_ws;

  int* cnt            = (int*)ws;                          // @0
  unsigned char* spec = (unsigned char*)(ws + 1024);       // 262144
  float* wvt          = (float*)(ws + 263168);             // 262144
  unsigned short* wkf = (unsigned short*)(ws + 525312);    // 131072
  float* scores       = (float*)(ws + 656384);             // 8388608
  int* rowinfo        = (int*)(ws + 9044992);              // 1048576
  int* rowlin         = (int*)(ws + 10093568);             // 1048576 -> ~11.1MB

  k_zero<<<1, 64, 0, stream>>>(cnt);
  k_prep<<<1024, 256, 0, stream>>>(raw, spec, out + N_Q * M_D, wv, wvt, wk, wkf,
                                   lin, cnt, rowinfo, rowlin);
  k_scores<<<4096, 256, 0, stream>>>(sv, q, wkf, pos, fq, cnt, rowinfo, rowlin, scores);
  k_vout<<<4096, 256, 0, stream>>>(sv, lin, spec, scores, wvt, out);
}

// Round 6
// 146.663 us; speedup vs baseline: 1.2080x; 1.0331x over previous
//
#include <hip/hip_runtime.h>
#include <math.h>

#define N_Q 4096
#define L_K 64
#define M_D 256

typedef float f32x16 __attribute__((ext_vector_type(16)));
typedef __bf16 b16x8 __attribute__((ext_vector_type(8)));
union F8 { uint4 u; unsigned short s[8]; b16x8 v; };

__device__ __forceinline__ unsigned short f2bf(float x) {
  unsigned u = __float_as_uint(x);
  return (unsigned short)((u + 0x7fffu + ((u >> 16) & 1u)) >> 16);  // RNE
}

__global__ void k_zero(int* __restrict__ c) { if (threadIdx.x == 0) c[0] = 0; }

// ---- prep: spec canonicalize + out2, Wv^T, Wk swizzled bf16 image, row compaction ----
__global__ __launch_bounds__(256) void k_prep(const unsigned char* __restrict__ raw,
                                              unsigned char* __restrict__ spec,
                                              float* __restrict__ out2,
                                              const float* __restrict__ wv,
                                              float* __restrict__ wvt,
                                              const float* __restrict__ wk,
                                              unsigned short* __restrict__ wkb,
                                              const int* __restrict__ lin,
                                              int* __restrict__ cnt,
                                              int* __restrict__ rowinfo,
                                              int* __restrict__ rowlin) {
  __shared__ int wbase[4];
  int v = 0;
  for (int i = threadIdx.x; i < 4096; i += 256)
    if (i & 3) v |= raw[i];
  int f = __syncthreads_or(v);            // 1 = byte layout, 0 = int32 layout
  const int gi = blockIdx.x * 256 + threadIdx.x;   // covers N*L = 262144
  const int lane = threadIdx.x & 63, w = threadIdx.x >> 6;
  bool b = f ? (raw[gi] != 0) : (((const int*)raw)[gi] != 0);
  spec[gi] = b ? 1 : 0;
  out2[gi] = b ? 1.0f : 0.0f;

  int li = lin[gi];
  unsigned long long mask = __ballot(b);
  if (lane == 0) wbase[w] = __popcll(mask);
  __syncthreads();
  if (threadIdx.x == 0) {                 // one atomic per block
    int t0 = wbase[0], t1 = wbase[1], t2 = wbase[2], t3 = wbase[3];
    int bs = atomicAdd(cnt, t0 + t1 + t2 + t3);
    wbase[0] = bs; wbase[1] = bs + t0; wbase[2] = bs + t0 + t1; wbase[3] = bs + t0 + t1 + t2;
  }
  __syncthreads();
  if (b) {
    int rank = __popcll(mask & ((1ull << lane) - 1));
    int p = wbase[w] + rank;
    rowinfo[p] = gi;                      // n*64 + l
    rowlin[p] = li;
  }

  if (gi < 65536) {
    wvt[(gi & 255) * 256 + (gi >> 8)] = wv[gi];    // wvt[j][m] = wv[m][j]
    // Wk bf16 image, pre-swizzled (R3-verified): half hh = k>>7, row n, 256B rows
    int n = gi >> 8, k = gi & 255;
    int hh = k >> 7, kl = k & 127;
    int slot = kl >> 3, bib = (kl & 7) << 1;
    int soff = hh * 65536 + n * 256 + (((slot ^ (n & 15)) << 4) | bib);
    *(unsigned short*)((char*)wkb + soff) = f2bf(wk[gi]);
  }
}

// ---- k_scores: swapped-operand K-proj GEMM (Wk in LDS) + register RoPE + scores ----
// 4096 blocks x 256 thr (4 waves). Wave (rg=w>>1, ch=w&1): 32 packed rows, heads ch*4..+3.
// A = Wk frags from swizzled LDS, B = per-lane gathered sv rows (4-deep prefetch).
__global__ __launch_bounds__(256, 2) void k_scores(
    const float* __restrict__ sv, const float* __restrict__ q,
    const unsigned short* __restrict__ wkb, const float* __restrict__ pos,
    const float* __restrict__ freqs, const int* __restrict__ cnt,
    const int* __restrict__ rowinfo, const int* __restrict__ rowlin,
    float* __restrict__ scores) {
  const int total = cnt[0];
  const int base = blockIdx.x * 64;
  if (base >= total) return;

  __shared__ __align__(16) char smem[65536];
  const int tid = threadIdx.x, lane = tid & 63, w = tid >> 6;
  const int c32 = lane & 31, kg = lane >> 5, hi = kg;
  const int ch = w & 1;

  const int idx = base + (w >> 1) * 32 + c32;
  const bool valid = idx < total;
  const int info = valid ? rowinfo[idx] : 0;                 // n*64+l (lane-local row)
  const float* brow = sv + (size_t)(valid ? rowlin[idx] : 0) * 256;

  // async stage of 64KB half hh (image pre-swizzled -> pure linear copy)
  auto stage = [&](int hh) {
    const char* src = (const char*)wkb + hh * 65536 + w * 16384 + lane * 16;
    char* dst = smem + w * 16384;          // wave-uniform base; HW adds lane*16
    #pragma unroll
    for (int i = 0; i < 16; ++i)
      __builtin_amdgcn_global_load_lds(
          (const __attribute__((address_space(1))) unsigned int*)(src + i * 1024),
          (__attribute__((address_space(3))) unsigned int*)(dst + i * 1024), 16, 0, 0);
  };

  f32x16 acc[4];
  #pragma unroll
  for (int t = 0; t < 4; ++t)
    #pragma unroll
    for (int r = 0; r < 16; ++r) acc[t][r] = 0.0f;

  stage(0);
  float4 pb[4][2];
  #pragma unroll
  for (int i = 0; i < 4; ++i) {            // 4-deep sv prefetch
    pb[i][0] = *(const float4*)(brow + i * 16 + kg * 8);
    pb[i][1] = *(const float4*)(brow + i * 16 + kg * 8 + 4);
  }
  asm volatile("s_waitcnt vmcnt(0)" ::: "memory");
  __syncthreads();

  auto gemm_half = [&](int hh) {
    #pragma unroll
    for (int ks = 0; ks < 8; ++ks) {
      const int gks = hh * 8 + ks;
      float4 b0v = pb[gks & 3][0], b1v = pb[gks & 3][1];
      if (gks + 4 < 16) {                  // static under full unroll
        pb[gks & 3][0] = *(const float4*)(brow + (gks + 4) * 16 + kg * 8);
        pb[gks & 3][1] = *(const float4*)(brow + (gks + 4) * 16 + kg * 8 + 4);
      }
      F8 bf;
      bf.s[0] = f2bf(b0v.x); bf.s[1] = f2bf(b0v.y); bf.s[2] = f2bf(b0v.z); bf.s[3] = f2bf(b0v.w);
      bf.s[4] = f2bf(b1v.x); bf.s[5] = f2bf(b1v.y); bf.s[6] = f2bf(b1v.z); bf.s[7] = f2bf(b1v.w);
      const unsigned kb = (unsigned)((ks * 16 + kg * 8) << 1);   // byte offset in 256B row
      #pragma unroll
      for (int t = 0; t < 4; ++t) {
        const int nc = (ch * 4 + t) * 32 + c32;                  // wk row (out channel)
        F8 af;
        af.u = *(const uint4*)(smem + nc * 256 + (kb ^ ((nc & 15) << 4)));
        acc[t] = __builtin_amdgcn_mfma_f32_32x32x16_bf16(af.v, bf.v, acc[t], 0, 0, 0);
      }
    }
  };

  gemm_half(0);
  __syncthreads();                         // all waves done reading half 0
  stage(1);
  asm volatile("s_waitcnt vmcnt(0)" ::: "memory");
  __syncthreads();
  gemm_half(1);

  // ---- in-register RoPE + q-dot (R5-verified); lane owns data row `info` ----
  const int nn_ = info >> 6, ll = info & 63;
  const float pp0 = pos[info * 3], pp1 = pos[info * 3 + 1], pp2 = pos[info * 3 + 2];
  #pragma unroll
  for (int t = 0; t < 4; ++t) {
    const int h = ch * 4 + t;
    const float* qh = q + nn_ * 256 + h * 32;
    const float* F = freqs + h * 16;       // F[p*128 + jj], jj = d/2
    float s = 0.f;
    #pragma unroll
    for (int g = 0; g < 4; ++g) {
      #pragma unroll
      for (int pr = 0; pr < 2; ++pr) {
        const int d0 = g * 8 + hi * 4 + pr * 2;
        const int jj = d0 >> 1;
        const int r = g * 4 + pr * 2;      // D row = (r&3)+8*(r>>2)+4*hi = d0
        float ke = acc[t][r], ko = acc[t][r + 1];
        float ang = pp0 * F[jj] + pp1 * F[128 + jj] + pp2 * F[256 + jj];
        float sn, cs;
        __sincosf(ang, &sn, &cs);
        float2 qq = *(const float2*)(qh + d0);
        s += ke * (cs * qq.x + sn * qq.y) + ko * (cs * qq.y - sn * qq.x);
      }
    }
    s += __shfl_xor(s, 32);
    if (hi == 0 && valid)
      scores[(nn_ * 8 + h) * 64 + ll] = s * 0.0625f;   // 1/sqrt(256)
  }
}

// ---- k_vout: softmax + compacted attn-weighted gather + Wv projection (1 n/block) ----
__global__ __launch_bounds__(256, 8) void k_vout(
    const float* __restrict__ sv, const int* __restrict__ lin,
    const unsigned char* __restrict__ spec, const float* __restrict__ scores,
    const float* __restrict__ wvt, float* __restrict__ out) {
  __shared__ float attn_s[64][8];
  __shared__ float agg_s[8][256];
  __shared__ int list_s[64];
  __shared__ int cnt_s;
  __shared__ int lin_l[64];
  __shared__ unsigned char spec_l[64];
  const int tid = threadIdx.x, lane = tid & 63, w = tid >> 6;
  const int n = blockIdx.x;

  if (tid < 64) {
    lin_l[tid] = lin[n * 64 + tid];
    spec_l[tid] = spec[n * 64 + tid];
  }
  __syncthreads();

  const bool sp = spec_l[lane] != 0;
  #pragma unroll
  for (int uu = 0; uu < 2; ++uu) {          // softmax: 8 heads, 2 per wave
    int h = w * 2 + uu;
    float v = sp ? scores[(n * 8 + h) * 64 + lane] : -__builtin_inff();
    float mx = v;
    #pragma unroll
    for (int o = 32; o; o >>= 1) mx = fmaxf(mx, __shfl_xor(mx, o));
    float e = sp ? __expf(v - mx) : 0.f;
    float sm = e;
    #pragma unroll
    for (int o = 32; o; o >>= 1) sm += __shfl_xor(sm, o);
    attn_s[lane][h] = (sm > 0.f) ? e / sm : 0.f;
  }
  if (w == 0) {                             // packed gather list
    unsigned long long mask = __ballot(sp);
    if (sp) {
      int rank = __popcll(mask & ((1ull << lane) - 1));
      list_s[rank] = (lin_l[lane] << 6) | lane;
    }
    if (lane == 0) cnt_s = __popcll(mask);
  }
  __syncthreads();

  const int m = tid;
  float ga[8];
  #pragma unroll
  for (int h = 0; h < 8; ++h) ga[h] = 0.f;
  const int cn = cnt_s;
  #pragma unroll 4
  for (int i = 0; i < cn; ++i) {
    int pk = list_s[i];
    float gv = sv[(size_t)(pk >> 6) * 256 + m];     // coalesced 1KB row
    const float4* ap = (const float4*)&attn_s[pk & 63][0];
    float4 aA = ap[0], aB = ap[1];                  // LDS broadcast
    ga[0] += aA.x * gv; ga[1] += aA.y * gv; ga[2] += aA.z * gv; ga[3] += aA.w * gv;
    ga[4] += aB.x * gv; ga[5] += aB.y * gv; ga[6] += aB.z * gv; ga[7] += aB.w * gv;
  }
  #pragma unroll
  for (int h = 0; h < 8; ++h) agg_s[h][m] = ga[h];
  __syncthreads();

  const int h = m >> 5;
  const float* ap = &agg_s[h][0];
  float o = 0.f;
  #pragma unroll 8
  for (int mm = 0; mm < 256; ++mm)
    o += ap[mm] * wvt[mm * 256 + m];        // broadcast LDS x coalesced L2
  out[n * 256 + m] = o;
}

extern "C" void kernel_launch(void* const* d_in, const int* in_sizes, int n_in,
                              void* d_out, int out_size, void* d_ws, size_t ws_size,
                              hipStream_t stream) {
  const float* sv  = (const float*)d_in[0];
  const int* lin   = (const int*)d_in[1];
  const unsigned char* raw = (const unsigned char*)d_in[2];
  const float* q   = (const float*)d_in[3];
  const float* wk  = (const float*)d_in[4];
  const float* wv  = (const float*)d_in[5];
  const float* pos = (const float*)d_in[6];
  const float* fq  = (const float*)d_in[7];
  float* out = (float*)d_out;
  char* ws = (char*)d_ws;

  int* cnt            = (int*)ws;                          // @0
  unsigned char* spec = (unsigned char*)(ws + 1024);       // 262144
  float* wvt          = (float*)(ws + 263168);             // 262144
  unsigned short* wkb = (unsigned short*)(ws + 525312);    // 131072
  float* scores       = (float*)(ws + 656384);             // 8388608
  int* rowinfo        = (int*)(ws + 9044992);              // 1048576
  int* rowlin         = (int*)(ws + 10093568);             // 1048576 -> ~11.1MB

  k_zero<<<1, 64, 0, stream>>>(cnt);
  k_prep<<<1024, 256, 0, stream>>>(raw, spec, out + N_Q * M_D, wv, wvt, wk, wkb,
                                   lin, cnt, rowinfo, rowlin);
  k_scores<<<4096, 256, 0, stream>>>(sv, q, wkb, pos, fq, cnt, rowinfo, rowlin, scores);
  k_vout<<<4096, 256, 0, stream>>>(sv, lin, spec, scores, wvt, out);
}

// Round 7
// 136.192 us; speedup vs baseline: 1.3009x; 1.0769x over previous
//
#include <hip/hip_runtime.h>
#include <math.h>

#define N_Q 4096
#define L_K 64
#define M_D 256

typedef float f32x16 __attribute__((ext_vector_type(16)));
typedef __bf16 b16x8 __attribute__((ext_vector_type(8)));
union F8 { uint4 u; unsigned short s[8]; b16x8 v; };

__device__ __forceinline__ unsigned short f2bf(float x) {
  unsigned u = __float_as_uint(x);
  return (unsigned short)((u + 0x7fffu + ((u >> 16) & 1u)) >> 16);  // RNE
}

// ---- prep: spec canonicalize + out2 echo, Wv^T, Wk quarter-swizzled bf16 image ----
__global__ __launch_bounds__(256) void k_prep(const unsigned char* __restrict__ raw,
                                              unsigned char* __restrict__ spec,
                                              float* __restrict__ out2,
                                              const float* __restrict__ wv,
                                              float* __restrict__ wvt,
                                              const float* __restrict__ wk,
                                              unsigned short* __restrict__ wkb) {
  int v = 0;
  for (int i = threadIdx.x; i < 4096; i += 256)
    if (i & 3) v |= raw[i];
  int f = __syncthreads_or(v);            // 1 = byte layout, 0 = int32 layout
  const int gi = blockIdx.x * 256 + threadIdx.x;   // covers N*L = 262144
  bool b = f ? (raw[gi] != 0) : (((const int*)raw)[gi] != 0);
  spec[gi] = b ? 1 : 0;
  out2[gi] = b ? 1.0f : 0.0f;
  if (gi < 65536) {
    wvt[(gi & 255) * 256 + (gi >> 8)] = wv[gi];    // wvt[j][m] = wv[m][j]
    // Wk quarter image: quarter qq = k>>6 (32KB each), 4 outcols per 512B macro-row,
    // 16B slot = ((kl>>3)*4 + (oc&3))  -> A-frag reads are 2-way max (free)
    int oc = gi >> 8, k = gi & 255;
    int qq = k >> 6, kl = k & 63;
    int addr = qq * 32768 + ((oc >> 2) << 9) + ((((kl >> 3) << 2) + (oc & 3)) << 4) + ((kl & 7) << 1);
    *(unsigned short*)((char*)wkb + addr) = f2bf(wk[gi]);
  }
}

// ---- k_fused: per-n {list build, coalesced gather->LDS bf16, K-proj MFMA,
//                RoPE+scores, softmax, V-agg} -> agg[n,8,256] bf16 ----
// LDS map: G [0,32768) | Wk quarter [32768,65536) | meta/scores/attn beyond.
#define WK_OFF  32768
#define LIN_OFF 65536
#define LL_OFF  65792
#define CNT_OFF 66048
#define SC_OFF  66304
#define AT_OFF  68352
#define LDS_SZ  70400

__global__ __launch_bounds__(256, 2) void k_fused(
    const float* __restrict__ sv, const int* __restrict__ lin,
    const unsigned char* __restrict__ spec, const float* __restrict__ q,
    const unsigned short* __restrict__ wkb, const float* __restrict__ pos,
    const float* __restrict__ freqs, unsigned short* __restrict__ agg) {
  __shared__ __align__(16) char smem[LDS_SZ];
  int* listlin = (int*)(smem + LIN_OFF);
  int* listl   = (int*)(smem + LL_OFF);
  int* cntp    = (int*)(smem + CNT_OFF);
  float* score_s = (float*)(smem + SC_OFF);   // [8][64] by packed index
  float* attn_s  = (float*)(smem + AT_OFF);   // [64][8]
  const int tid = threadIdx.x, lane = tid & 63, w = tid >> 6;
  const int c32 = lane & 31, kg = lane >> 5;
  const int n = blockIdx.x;

  if (w == 0) {                               // wave 0 builds the packed list
    bool sp = spec[n * 64 + lane] != 0;
    int li = lin[n * 64 + lane];
    unsigned long long mask = __ballot(sp);
    if (sp) {
      int rank = __popcll(mask & ((1ull << lane) - 1));
      listl[rank] = lane;
      listlin[rank] = li;
    }
    if (lane == 0) cntp[0] = __popcll(mask);
  }
  __syncthreads();
  const int cnt = cntp[0];
  if (cnt == 0) {                             // no keys: agg row = 0
    *(uint4*)((char*)agg + (size_t)n * 4096 + tid * 16) = uint4{0, 0, 0, 0};
    return;
  }
  const int rtc = (cnt + 31) >> 5;            // 1 or 2 row-tiles

  // issue Wk quarter 0 (async DMA), then stage G rows coalesced (f32 -> bf16)
  {
    const char* src = (const char*)wkb + w * 8192 + lane * 16;
    char* dst = smem + WK_OFF + w * 8192;
    #pragma unroll
    for (int i2 = 0; i2 < 8; ++i2)
      __builtin_amdgcn_global_load_lds(
          (const __attribute__((address_space(1))) unsigned int*)(src + i2 * 1024),
          (__attribute__((address_space(3))) unsigned int*)(dst + i2 * 1024), 16, 0, 0);
  }
  {
    const int ii = tid & 31, pr0 = tid >> 5;  // 32 thr per row, 8 rows per pass
    for (int p = pr0; p < cnt; p += 8) {
      const float* srow = sv + (size_t)listlin[p] * 256 + ii * 8;
      float4 f0 = *(const float4*)srow;
      float4 f1 = *(const float4*)(srow + 4);
      F8 pk;
      pk.s[0] = f2bf(f0.x); pk.s[1] = f2bf(f0.y); pk.s[2] = f2bf(f0.z); pk.s[3] = f2bf(f0.w);
      pk.s[4] = f2bf(f1.x); pk.s[5] = f2bf(f1.y); pk.s[6] = f2bf(f1.z); pk.s[7] = f2bf(f1.w);
      *(uint4*)(smem + p * 512 + ((ii ^ (p & 31)) << 4)) = pk.u;    // XOR-swizzled slot
    }
  }
  asm volatile("s_waitcnt vmcnt(0)" ::: "memory");
  __syncthreads();

  f32x16 acc[2][2];
  #pragma unroll
  for (int a = 0; a < 2; ++a)
    #pragma unroll
    for (int b2 = 0; b2 < 2; ++b2)
      #pragma unroll
      for (int r = 0; r < 16; ++r) acc[a][b2][r] = 0.0f;

  #pragma unroll
  for (int qq = 0; qq < 4; ++qq) {
    #pragma unroll
    for (int ksq = 0; ksq < 4; ++ksq) {
      const int slot = qq * 8 + ksq * 2 + kg;          // G 16B-slot index (k>>3)
      F8 b0, b1;
      b0.u = *(const uint4*)(smem + c32 * 512 + ((slot ^ c32) << 4));
      if (rtc > 1)
        b1.u = *(const uint4*)(smem + (32 + c32) * 512 + ((slot ^ c32) << 4));
      const int sA = (ksq * 2 + kg) << 2;
      #pragma unroll
      for (int ctl = 0; ctl < 2; ++ctl) {
        const int nc = (w * 2 + ctl) * 32 + c32;       // out channel
        F8 af;
        af.u = *(const uint4*)(smem + WK_OFF + ((nc >> 2) << 9) + ((sA + (nc & 3)) << 4));
        acc[0][ctl] = __builtin_amdgcn_mfma_f32_32x32x16_bf16(af.v, b0.v, acc[0][ctl], 0, 0, 0);
        if (rtc > 1)
          acc[1][ctl] = __builtin_amdgcn_mfma_f32_32x32x16_bf16(af.v, b1.v, acc[1][ctl], 0, 0, 0);
      }
    }
    if (qq < 3) {                           // restage next Wk quarter
      __syncthreads();
      const char* src = (const char*)wkb + (qq + 1) * 32768 + w * 8192 + lane * 16;
      char* dst = smem + WK_OFF + w * 8192;
      #pragma unroll
      for (int i2 = 0; i2 < 8; ++i2)
        __builtin_amdgcn_global_load_lds(
            (const __attribute__((address_space(1))) unsigned int*)(src + i2 * 1024),
            (__attribute__((address_space(3))) unsigned int*)(dst + i2 * 1024), 16, 0, 0);
      asm volatile("s_waitcnt vmcnt(0)" ::: "memory");
      __syncthreads();
    }
  }

  // ---- in-register RoPE + q-dot (R5-verified mapping); lane owns packed row p ----
  #pragma unroll
  for (int rt = 0; rt < 2; ++rt) {
    if (rt < rtc) {
      const int p = rt * 32 + c32;
      const bool valid = p < cnt;
      const int l = valid ? listl[p] : 0;
      const float* lp = pos + ((size_t)n * 64 + l) * 3;
      const float pp0 = lp[0], pp1 = lp[1], pp2 = lp[2];
      #pragma unroll
      for (int ctl = 0; ctl < 2; ++ctl) {
        const int h = w * 2 + ctl;
        const float* qh = q + n * 256 + h * 32;
        const float* F = freqs + h * 16;
        float s = 0.f;
        #pragma unroll
        for (int g = 0; g < 4; ++g) {
          #pragma unroll
          for (int pr = 0; pr < 2; ++pr) {
            const int d0 = g * 8 + kg * 4 + pr * 2;    // D row of reg r == d0
            const int jj = d0 >> 1;
            const int r = g * 4 + pr * 2;
            float ke = acc[rt][ctl][r], ko = acc[rt][ctl][r + 1];
            float ang = pp0 * F[jj] + pp1 * F[128 + jj] + pp2 * F[256 + jj];
            float sn, cs;
            __sincosf(ang, &sn, &cs);
            float2 qq2 = *(const float2*)(qh + d0);
            s += ke * (cs * qq2.x + sn * qq2.y) + ko * (cs * qq2.y - sn * qq2.x);
          }
        }
        s += __shfl_xor(s, 32);
        if (kg == 0 && valid) score_s[h * 64 + p] = s * 0.0625f;   // 1/sqrt(256)
      }
    }
  }
  __syncthreads();

  // ---- softmax over packed rows (all specified by construction) ----
  #pragma unroll
  for (int uu = 0; uu < 2; ++uu) {
    const int h = w * 2 + uu;
    const bool vl = lane < cnt;
    float v = vl ? score_s[h * 64 + lane] : -__builtin_inff();
    float mx = v;
    #pragma unroll
    for (int o = 32; o; o >>= 1) mx = fmaxf(mx, __shfl_xor(mx, o));
    float e = vl ? __expf(v - mx) : 0.f;
    float sm = e;
    #pragma unroll
    for (int o = 32; o; o >>= 1) sm += __shfl_xor(sm, o);
    attn_s[lane * 8 + h] = e / sm;           // cnt>=1 -> sm>0
  }
  __syncthreads();

  // ---- V-agg from the SAME G tile: ga[h] = sum_p attn[p][h] * G[p][m] ----
  const int m = tid;
  float ga[8];
  #pragma unroll
  for (int h = 0; h < 8; ++h) ga[h] = 0.f;
  for (int p = 0; p < cnt; ++p) {
    unsigned short us = *(const unsigned short*)(smem + p * 512 +
                          ((((m >> 3) ^ (p & 31)) << 4) | ((m & 7) << 1)));
    float gv = __uint_as_float((unsigned)us << 16);
    const float4* ap = (const float4*)(attn_s + p * 8);
    float4 aA = ap[0], aB = ap[1];
    ga[0] += aA.x * gv; ga[1] += aA.y * gv; ga[2] += aA.z * gv; ga[3] += aA.w * gv;
    ga[4] += aB.x * gv; ga[5] += aB.y * gv; ga[6] += aB.z * gv; ga[7] += aB.w * gv;
  }
  #pragma unroll
  for (int h = 0; h < 8; ++h)
    agg[(size_t)n * 2048 + h * 256 + m] = f2bf(ga[h]);
}

// ---- k_out: out[n,m] = sum_j agg[n, h(m), j] * Wv[m, j]; 4 n per block ----
__global__ __launch_bounds__(256) void k_out(const unsigned short* __restrict__ agg,
                                             const float* __restrict__ wvt,
                                             float* __restrict__ out) {
  __shared__ float a_s[4][8][260];            // +4 pad: h-stride 260 words
  const int tid = threadIdx.x;
  const int n0 = blockIdx.x * 4;
  #pragma unroll
  for (int it = 0; it < 4; ++it) {
    uint4 v = *(const uint4*)(agg + (size_t)(n0 + it) * 2048 + tid * 8);
    const unsigned short* sp = (const unsigned short*)&v;
    const int hh = tid >> 5, m0 = (tid & 31) * 8;
    #pragma unroll
    for (int k2 = 0; k2 < 8; ++k2)
      a_s[it][hh][m0 + k2] = __uint_as_float((unsigned)sp[k2] << 16);
  }
  __syncthreads();
  const int m = tid, h = m >> 5;
  float o0 = 0.f, o1 = 0.f, o2 = 0.f, o3 = 0.f;
  #pragma unroll 8
  for (int j = 0; j < 256; ++j) {
    float wvv = wvt[j * 256 + m];             // coalesced, L2-hot
    o0 += a_s[0][h][j] * wvv;
    o1 += a_s[1][h][j] * wvv;
    o2 += a_s[2][h][j] * wvv;
    o3 += a_s[3][h][j] * wvv;
  }
  out[(n0 + 0) * 256 + m] = o0;
  out[(n0 + 1) * 256 + m] = o1;
  out[(n0 + 2) * 256 + m] = o2;
  out[(n0 + 3) * 256 + m] = o3;
}

extern "C" void kernel_launch(void* const* d_in, const int* in_sizes, int n_in,
                              void* d_out, int out_size, void* d_ws, size_t ws_size,
                              hipStream_t stream) {
  const float* sv  = (const float*)d_in[0];
  const int* lin   = (const int*)d_in[1];
  const unsigned char* raw = (const unsigned char*)d_in[2];
  const float* q   = (const float*)d_in[3];
  const float* wk  = (const float*)d_in[4];
  const float* wv  = (const float*)d_in[5];
  const float* pos = (const float*)d_in[6];
  const float* fq  = (const float*)d_in[7];
  float* out = (float*)d_out;
  char* ws = (char*)d_ws;

  unsigned char* spec = (unsigned char*)ws;               // 262144
  float* wvt          = (float*)(ws + 262144);            // 262144
  unsigned short* wkb = (unsigned short*)(ws + 524288);   // 131072
  unsigned short* agg = (unsigned short*)(ws + 655360);   // 16777216 -> ~17.4MB total

  k_prep <<<1024, 256, 0, stream>>>(raw, spec, out + N_Q * M_D, wv, wvt, wk, wkb);
  k_fused<<<4096, 256, 0, stream>>>(sv, lin, spec, q, wkb, pos, fq, agg);
  k_out  <<<1024, 256, 0, stream>>>(agg, wvt, out);
}